// Round 7
// baseline (136.409 us; speedup 1.0000x reference)
//
#include <hip/hip_runtime.h>

#define DEV __device__ __forceinline__

// ---------------------------------------------------------------------------
// R7: unified gate chain. Each 16-lane group holds ONE STATE (psi0 or psi1)
// of one element: grp = lane>>4; elem = blk*8 + wave*2 + (grp>>1);
// st = grp&1 (0 -> psi0/conv weights, 1 -> psi1/CRX weights).
// psi0's entangler and psi1's CRX ladder have IDENTICAL pair structure; the
// u4_g 2-gather decomposition is exact for any 4x4, so one instruction
// stream serves both states with a per-group LDS weight base (no divergence).
// Encode is computed per-group (SIMT-free duplication). 8192 elems ->
// 4096 waves = 4 waves/SIMD (R6 was 2 -> latency-bound at VALUBusy 45%).
// Layout (from R5/R6, correctness-verified): 16 amps/lane, j=(sub<<4)|s;
// q0,q2,q4,q6 -> lane bits 3..0; q1,q3,q5,q7 -> s bits 3..0. All encode
// CNOTs folded into per-gate XOR pair masks (LM,SM) + parity masks (LR,SR).
// __launch_bounds__(256,2): the only bound that yields sane (spill-free)
// allocation for this live set (R2/R5 showed tighter bounds -> 60-270 MB
// scratch traffic).
// ---------------------------------------------------------------------------

DEV int lpar(int lane, int m) { return __builtin_popcount(lane & m) & 1; }
constexpr int cpar(int v) { return (v ^ (v >> 1) ^ (v >> 2) ^ (v >> 3)) & 1; }

// ---- real RY with general pair mask / parity ------------------------------
template<int LM, int SM, int LR, int SR>
DEV void ryr(float* p, float gc, float gs, int lane) {
  const float sg0 = lpar(lane, LR) ? gs : -gs;   // sign when cpar(s&SR)==0
  const float sg1 = -sg0;
  if constexpr (LM != 0) {
    float t[16];
    #pragma unroll
    for (int s = 0; s < 16; ++s) t[s] = __shfl_xor(p[s ^ SM], LM);
    #pragma unroll
    for (int s = 0; s < 16; ++s)
      p[s] = gc * p[s] + (cpar(s & SR) ? sg1 : sg0) * t[s];
  } else {
    constexpr int LOW = SM & (-SM);
    #pragma unroll
    for (int s = 0; s < 16; ++s) if (!(s & LOW)) {
      const int s1 = s ^ SM;
      float a = p[s], b = p[s1];
      float sg = cpar(s & SR) ? sg1 : sg0;
      p[s]  = gc * a + sg * b;
      p[s1] = gc * b - sg * a;
    }
  }
}

// ---- complex U3: u[8] = {u00r,u00i,u01r,u01i,u10r,u10i,u11r,u11i} --------
template<int LM, int SM, int LR, int SR>
DEV void u3_g(float* pr, float* pi, const float* u, int lane) {
  const bool hl = lpar(lane, LR);
  const float d0r = hl ? u[6] : u[0], d0i = hl ? u[7] : u[1];
  const float o0r = hl ? u[4] : u[2], o0i = hl ? u[5] : u[3];
  const float d1r = hl ? u[0] : u[6], d1i = hl ? u[1] : u[7];
  const float o1r = hl ? u[2] : u[4], o1i = hl ? u[3] : u[5];
  if constexpr (LM != 0) {
    float tr[16], ti[16];
    #pragma unroll
    for (int s = 0; s < 16; ++s) {
      tr[s] = __shfl_xor(pr[s ^ SM], LM);
      ti[s] = __shfl_xor(pi[s ^ SM], LM);
    }
    #pragma unroll
    for (int s = 0; s < 16; ++s) {
      const bool c1 = cpar(s & SR);
      const float dr = c1 ? d1r : d0r, di = c1 ? d1i : d0i;
      const float orr = c1 ? o1r : o0r, oi = c1 ? o1i : o0i;
      float ar = pr[s], ai = pi[s];
      pr[s] = dr*ar - di*ai + orr*tr[s] - oi*ti[s];
      pi[s] = dr*ai + di*ar + orr*ti[s] + oi*tr[s];
    }
  } else {
    constexpr int LOW = SM & (-SM);
    #pragma unroll
    for (int s = 0; s < 16; ++s) if (!(s & LOW)) {
      const int s1 = s ^ SM;
      const bool c1 = cpar(s & SR);
      const float dAr = c1 ? d1r : d0r, dAi = c1 ? d1i : d0i;
      const float oAr = c1 ? o1r : o0r, oAi = c1 ? o1i : o0i;
      const float dBr = c1 ? d0r : d1r, dBi = c1 ? d0i : d1i;
      const float oBr = c1 ? o0r : o1r, oBi = c1 ? o0i : o1i;
      float ar = pr[s], ai = pi[s], br = pr[s1], bi = pi[s1];
      pr[s]  = dAr*ar - dAi*ai + oAr*br - oAi*bi;
      pi[s]  = dAr*ai + dAi*ar + oAr*bi + oAi*br;
      pr[s1] = dBr*br - dBi*bi + oBr*ar - oBi*ai;
      pi[s1] = dBr*bi + dBi*br + oBr*ai + oBi*ar;
    }
  }
}

// ---- general 4x4 two-qubit gate, 2-gather decomposition -------------------
#define U4CLASS(Q)                                                            \
  if constexpr (!(((SRc == 0) && (Q & 2)) || ((SRt == 0) && (Q & 1)))) {      \
    const int r1 = R ^ Q, r2 = r1 ^ 2;                                        \
    const float2 wd = w2[r1 * 4 + r1],       wo = w2[r1 * 4 + (r1 ^ 1)];      \
    const float2 vd = w2[r2 * 4 + r1],       vo = w2[r2 * 4 + (r1 ^ 1)];      \
    _Pragma("unroll")                                                         \
    for (int s = 0; s < 16; ++s)                                              \
      if (((cpar(s & SRc) << 1) | cpar(s & SRt)) == Q) {                      \
        float ar = pr[s], ai = pi[s], br = tr[s], bi = ti[s];                 \
        pr[s] = wd.x*ar - wd.y*ai + wo.x*br - wo.y*bi;                        \
        pi[s] = wd.x*ai + wd.y*ar + wo.x*bi + wo.y*br;                        \
        tr[s] = vd.x*ar - vd.y*ai + vo.x*br - vo.y*bi;                        \
        ti[s] = vd.x*ai + vd.y*ar + vo.x*bi + vo.y*br;                        \
      }                                                                       \
  }

template<int LMc, int SMc, int LMt, int SMt, int LRc, int SRc, int LRt, int SRt>
DEV void u4_g(float* pr, float* pi, const float2* w2, int lane) {
  const int R = (lpar(lane, LRc) << 1) | lpar(lane, LRt);
  float tr[16], ti[16];
  #pragma unroll
  for (int s = 0; s < 16; ++s) {
    float vr = pr[s ^ SMt], vi = pi[s ^ SMt];
    if constexpr (LMt != 0) { vr = __shfl_xor(vr, LMt); vi = __shfl_xor(vi, LMt); }
    tr[s] = vr; ti[s] = vi;
  }
  U4CLASS(0) U4CLASS(1) U4CLASS(2) U4CLASS(3)
  #pragma unroll
  for (int s = 0; s < 16; ++s) {
    float br = tr[s ^ SMc], bi = ti[s ^ SMc];
    if constexpr (LMc != 0) { br = __shfl_xor(br, LMc); bi = __shfl_xor(bi, LMc); }
    pr[s] += br; pi[s] += bi;
  }
}

// ---- U3 coefficient build -------------------------------------------------
DEV void u3_make(float t, float p, float l, float* u) {
  float c = __cosf(0.5f * t), s = __sinf(0.5f * t);
  float cp = __cosf(p), sp = __sinf(p);
  float cl = __cosf(l), sl = __sinf(l);
  float cpl = __cosf(p + l), spl = __sinf(p + l);
  u[0] = c;        u[1] = 0.0f;
  u[2] = -cl * s;  u[3] = -sl * s;
  u[4] = cp * s;   u[5] = sp * s;
  u[6] = cpl * c;  u[7] = spl * c;
}

// ---- <Z3>,<Z7>: r3 = (LR=10,SR=1), r7 = (LR=10,SR=0) ----------------------
DEV void expz_fin(const float* pr, const float* pi, int lane, float& z3, float& z7) {
  float t3 = 0.0f, t7 = 0.0f;
  #pragma unroll
  for (int s = 0; s < 16; ++s) {
    float p = pr[s] * pr[s] + pi[s] * pi[s];
    t7 += p;
    t3 += (s & 1) ? -p : p;
  }
  if (lpar(lane, 10)) { t3 = -t3; t7 = -t7; }
  #pragma unroll
  for (int m = 1; m < 16; m <<= 1) {
    t3 += __shfl_xor(t3, m);
    t7 += __shfl_xor(t7, m);
  }
  z3 = t3; z7 = t7;
}

// ---------------------------------------------------------------------------

__global__ __launch_bounds__(256, 2)
void qcnn_kernel(const float* __restrict__ x,
                 const float* __restrict__ rz_p, const float* __restrict__ ry_p,
                 const float* __restrict__ ry2_p, const float* __restrict__ crx_p,
                 const float* __restrict__ u3_p, const float* __restrict__ u3b_p,
                 const float* __restrict__ W1, const float* __restrict__ b1,
                 const float* __restrict__ W2, const float* __restrict__ b2,
                 float* __restrict__ out, int B) {
  // cw: [layer][state][16 complex]  (state 0 = fused conv U4, 1 = CRX-as-4x4)
  __shared__ __align__(8) float cw[128];

  const int tid  = threadIdx.x;
  const int lane = tid & 63;
  const int wave = tid >> 6;
  const int grp  = lane >> 4;
  const int sub  = lane & 15;
  const int st   = grp & 1;              // 0 -> psi0, 1 -> psi1
  const int gb   = lane & 48;
  const int elem = blockIdx.x * 8 + wave * 2 + (grp >> 1);
  const int elemc = elem < B ? elem : (B - 1);

  // ---- weight build (wave 0): lanes 0..31 conv-U4, lanes 32..63 CRX ------
  if (tid < 32) {
    const int lay = tid >> 4, e = tid & 15, i4 = e >> 2, j4 = e & 3;
    const int base = tid & 48;
    const float c45 = 0.70710678118654752f;
    float rz = rz_p[lay], ry = ry_p[lay], ry2 = ry2_p[lay];
    float mr = (i4 == j4) ? c45 : 0.0f;
    float mi = (i4 == j4) ? ((i4 & 1) ? -c45 : c45) : 0.0f;
    { int t = (i4 & 1) ? (i4 ^ 2) : i4; int src = base | (t << 2) | j4;
      mr = __shfl(mr, src); mi = __shfl(mi, src); }
    { float cz = __cosf(0.5f * rz), sz = __sinf(0.5f * rz);
      float di = (i4 & 2) ? sz : -sz;
      float nr = cz * mr - di * mi, ni = cz * mi + di * mr; mr = nr; mi = ni; }
    { float cy = __cosf(0.5f * ry), sy = __sinf(0.5f * ry);
      int src = base | ((i4 ^ 1) << 2) | j4;
      float orr = __shfl(mr, src), oii = __shfl(mi, src);
      float sg = (i4 & 1) ? sy : -sy;
      mr = cy * mr + sg * orr; mi = cy * mi + sg * oii; }
    { int t = (i4 & 2) ? (i4 ^ 1) : i4; int src = base | (t << 2) | j4;
      mr = __shfl(mr, src); mi = __shfl(mi, src); }
    { float cy = __cosf(0.5f * ry2), sy = __sinf(0.5f * ry2);
      int src = base | ((i4 ^ 1) << 2) | j4;
      float orr = __shfl(mr, src), oii = __shfl(mi, src);
      float sg = (i4 & 1) ? sy : -sy;
      mr = cy * mr + sg * orr; mi = cy * mi + sg * oii; }
    { int t = (i4 & 1) ? (i4 ^ 2) : i4; int src = base | (t << 2) | j4;
      mr = __shfl(mr, src); mi = __shfl(mi, src); }
    { float di = (i4 & 2) ? c45 : -c45;
      float nr = c45 * mr - di * mi, ni = c45 * mi + di * mr; mr = nr; mi = ni; }
    cw[((lay * 2 + 0) * 16 + e) * 2]     = mr;
    cw[((lay * 2 + 0) * 16 + e) * 2 + 1] = mi;
  } else if (tid < 64) {
    const int t2 = tid - 32;
    const int lay = t2 >> 4, e = t2 & 15, i4 = e >> 2, j4 = e & 3;
    float t = crx_p[lay];
    float c = __cosf(0.5f * t), s = __sinf(0.5f * t);
    float mr = 0.0f, mi = 0.0f;
    if (i4 == j4) mr = (i4 < 2) ? 1.0f : c;
    if ((i4 >= 2) && ((i4 ^ j4) == 1)) mi = -s;
    cw[((lay * 2 + 1) * 16 + e) * 2]     = mr;
    cw[((lay * 2 + 1) * 16 + e) * 2 + 1] = mi;
  }

  // ---- angles: lane sub holds angles 2*sub, 2*sub+1 of its element --------
  float2 aa = ((const float2*)x)[(size_t)elemc * 16 + sub];
  float ch0 = __cosf(0.5f * aa.x), sh0 = __sinf(0.5f * aa.x);
  float ch1 = __cosf(0.5f * aa.y), sh1 = __sinf(0.5f * aa.y);

  float cq[8], sq[8];
  #pragma unroll
  for (int q = 0; q < 8; ++q) {
    cq[q] = __shfl((q & 1) ? ch1 : ch0, gb | (q >> 1));
    sq[q] = __shfl((q & 1) ? sh1 : sh0, gb | (q >> 1));
  }

  // ---- product-state init (cycle-1 RYs; state real) -----------------------
  float p[16];
  {
    float g = ((sub & 8) ? sq[0] : cq[0]) * ((sub & 4) ? sq[2] : cq[2]) *
              ((sub & 2) ? sq[4] : cq[4]) * ((sub & 1) ? sq[6] : cq[6]);
    float h13[4] = {cq[1]*cq[3], cq[1]*sq[3], sq[1]*cq[3], sq[1]*sq[3]};
    float h57[4] = {cq[5]*cq[7], cq[5]*sq[7], sq[5]*cq[7], sq[5]*sq[7]};
    #pragma unroll
    for (int i = 0; i < 4; ++i) h13[i] *= g;
    #pragma unroll
    for (int s = 0; s < 16; ++s) p[s] = h13[s >> 2] * h57[s & 3];
  }

  // ---- encode cycles 2..4 (24 real RYs, CNOTs folded into masks) ----------
  #define ENC(k, LM, SM, LR, SR) {                                  \
    float gc = __shfl(((k) & 1) ? ch1 : ch0, gb | ((k) >> 1));      \
    float gs = __shfl(((k) & 1) ? sh1 : sh0, gb | ((k) >> 1));      \
    ryr<LM, SM, LR, SR>(p, gc, gs, lane); }

  ENC(8,  8,8, 7,15)  ENC(9,  4,8, 8,8)   ENC(10, 4,4, 12,8)  ENC(11, 2,4, 12,12)
  ENC(12, 2,2, 14,12) ENC(13, 1,2, 14,14) ENC(14, 1,1, 15,14) ENC(15, 8,9, 15,15)
  ENC(16, 12,0, 8,15) ENC(17, 0,12, 15,7) ENC(18, 6,0, 3,15)  ENC(19, 0,6, 15,3)
  ENC(20, 3,0, 1,15)  ENC(21, 0,3, 15,1)  ENC(22, 9,8, 0,15)  ENC(23, 4,9, 15,0)
  ENC(24, 12,12, 2,10) ENC(25, 6,12, 7,8) ENC(26, 6,6, 4,7)   ENC(27, 3,6, 11,4)
  ENC(28, 3,3, 10,11)  ENC(29, 9,11, 5,10) ENC(30, 13,1, 5,5) ENC(31, 8,5, 10,5)
  #undef ENC

  float pi_[16];
  #pragma unroll
  for (int s = 0; s < 16; ++s) pi_[s] = 0.0f;

  __syncthreads();  // cw ready
  const float2* w0 = ((const float2*)cw) + (0 * 2 + st) * 16;
  const float2* w1 = ((const float2*)cw) + (1 * 2 + st) * 16;

  // ---- unified gate chain (same structure for psi0 and psi1) --------------
  u4_g<10,0,  0,10, 8,10, 5,2 >(p, pi_, w0, lane);   // (0,1)
  u4_g<5,0,   0,5,  1,5,  10,1>(p, pi_, w0, lane);   // (2,3)
  u4_g<10,8,  4,10, 0,10, 5,0 >(p, pi_, w0, lane);   // (4,5)
  u4_g<5,4,   2,5,  0,5,  10,0>(p, pi_, w0, lane);   // (6,7)
  u4_g<0,10,  5,0,  5,2,  1,5 >(p, pi_, w0, lane);   // (1,2)
  u4_g<0,5,   10,8, 10,1, 0,10>(p, pi_, w0, lane);   // (3,4)
  u4_g<4,10,  5,4,  5,0,  0,5 >(p, pi_, w0, lane);   // (5,6)
  {
    float ua[8], ub[8], us[8];
    u3_make(u3_p[0], u3_p[1], u3_p[2], ua);
    u3_make(u3b_p[0], u3b_p[1], u3b_p[2], ub);
    #pragma unroll
    for (int k = 0; k < 8; ++k) us[k] = st ? ub[k] : ua[k];
    u3_g<0,10, 5,2 >(p, pi_, us, lane);   // q1
    u3_g<0,5,  10,1>(p, pi_, us, lane);   // q3
    u3_g<4,10, 5,0 >(p, pi_, us, lane);   // q5
    u3_g<2,5,  10,0>(p, pi_, us, lane);   // q7
  }
  u4_g<0,10,  0,5,  5,2,  10,1>(p, pi_, w1, lane);   // (1,3)
  u4_g<4,10,  2,5,  5,0,  10,0>(p, pi_, w1, lane);   // (5,7)
  u4_g<0,5,   4,10, 10,1, 5,0 >(p, pi_, w1, lane);   // (3,5)
  {
    float ua[8], ub[8], us[8];
    u3_make(u3_p[3], u3_p[4], u3_p[5], ua);
    u3_make(u3b_p[3], u3b_p[4], u3b_p[5], ub);
    #pragma unroll
    for (int k = 0; k < 8; ++k) us[k] = st ? ub[k] : ua[k];
    u3_g<0,5,  10,1>(p, pi_, us, lane);   // q3
    u3_g<2,5,  10,0>(p, pi_, us, lane);   // q7
  }

  // ---- features: own (z3,z7) + partner state's via cross-group shuffle ----
  float z3, z7;
  expz_fin(p, pi_, lane, z3, z7);
  float o3 = __shfl_xor(z3, 16);
  float o7 = __shfl_xor(z7, 16);
  const float f0 = st ? o3 : z3, f1 = st ? o7 : z7;
  const float f2 = st ? z3 : o3, f3 = st ? z7 : o7;

  // ---- MLP: lane j (=sub, j<15) computes hidden unit j --------------------
  const int j = (sub < 15) ? sub : 0;
  float acc = W1[j * 4 + 0] * f0 + W1[j * 4 + 1] * f1 +
              W1[j * 4 + 2] * f2 + W1[j * 4 + 3] * f3 + b1[j];
  float e2 = __expf(2.0f * acc);
  float th = (e2 - 1.0f) / (e2 + 1.0f);
  float part = (sub < 15) ? th * W2[j] : 0.0f;
  #pragma unroll
  for (int m = 1; m < 16; m <<= 1) part += __shfl_xor(part, m);

  if (sub == 0 && st == 0 && elem < B) {
    float z = part + b2[0];
    out[elem] = 1.0f / (1.0f + __expf(-z));
  }
}

extern "C" void kernel_launch(void* const* d_in, const int* in_sizes, int n_in,
                              void* d_out, int out_size, void* d_ws, size_t ws_size,
                              hipStream_t stream) {
  (void)n_in; (void)out_size; (void)d_ws; (void)ws_size;
  const float* x     = (const float*)d_in[0];
  const float* rz_p  = (const float*)d_in[1];
  const float* ry_p  = (const float*)d_in[2];
  const float* ry2_p = (const float*)d_in[3];
  const float* crx_p = (const float*)d_in[4];
  const float* u3_p  = (const float*)d_in[5];
  const float* u3b_p = (const float*)d_in[6];
  const float* W1    = (const float*)d_in[7];
  const float* b1    = (const float*)d_in[8];
  const float* W2    = (const float*)d_in[9];
  const float* b2    = (const float*)d_in[10];
  float* out = (float*)d_out;

  const int B = in_sizes[0] / 32;          // 8192
  const int blocks = (B + 7) / 8;          // 2 elems/wave (4 states), 4 waves
  qcnn_kernel<<<dim3(blocks), dim3(256), 0, stream>>>(
      x, rz_p, ry_p, ry2_p, crx_p, u3_p, u3b_p, W1, b1, W2, b2, out, B);
}

// Round 8
// 132.925 us; speedup vs baseline: 1.0262x; 1.0262x over previous
//
#include <hip/hip_runtime.h>

#define DEV __device__ __forceinline__

// ---------------------------------------------------------------------------
// R8: R6's algorithm (lazy-CNOT GF2 folding, real encode, 2-gather U4) at
// HALF the wave granularity: 32 lanes per element (lane bit5 = element),
// 8 amps/lane. 8192 elems -> 4096 waves = 4 waves/SIMD (R6 was 2048 -> 2,
// latency-bound at VALUBusy 45%). Work per element identical to R6; no
// psi0/psi1 duplication (R7's mistake).
// Index: j = (l5<<3)|s, l5 = lane&31, s in [0,8).
//   l5 bits 4..1 = q0,q2,q4,q6 ; l5 bit 0 = q1 ; s bits 2..0 = q3,q5,q7.
// Masks are the R5/R6 (verified) masks transformed by moving S-bit3 into the
// lane: LM' = (LM<<1)|(SM>>3), SM' = SM&7; same rule for LR/SR.
// Both chains (conv fused-U4 / CRX-as-4x4) share one u4_g code path with
// per-iteration LDS weight tables (R7-verified identical pair structure).
// __launch_bounds__(256,2): only bound observed to give spill-free alloc.
// ---------------------------------------------------------------------------

DEV int lpar(int lane, int m) { return __builtin_popcount(lane & m) & 1; }
constexpr int cpar3(int v) { return (v ^ (v >> 1) ^ (v >> 2)) & 1; }

// ---- real RY with general pair mask / parity ------------------------------
template<int LM, int SM, int LR, int SR>
DEV void ryr(float* p, float gc, float gs, int lane) {
  const float sg0 = lpar(lane, LR) ? gs : -gs;   // sign when cpar3(s&SR)==0
  const float sg1 = -sg0;
  if constexpr (LM != 0) {
    float t[8];
    #pragma unroll
    for (int s = 0; s < 8; ++s) t[s] = __shfl_xor(p[s ^ SM], LM);
    #pragma unroll
    for (int s = 0; s < 8; ++s)
      p[s] = gc * p[s] + (cpar3(s & SR) ? sg1 : sg0) * t[s];
  } else {
    constexpr int LOW = SM & (-SM);
    #pragma unroll
    for (int s = 0; s < 8; ++s) if (!(s & LOW)) {
      const int s1 = s ^ SM;
      float a = p[s], b = p[s1];
      float sg = cpar3(s & SR) ? sg1 : sg0;
      p[s]  = gc * a + sg * b;
      p[s1] = gc * b - sg * a;
    }
  }
}

// ---- complex U3: u[8] = {u00r,u00i,u01r,u01i,u10r,u10i,u11r,u11i} --------
template<int LM, int SM, int LR, int SR>
DEV void u3_g(float* pr, float* pi, const float* u, int lane) {
  const bool hl = lpar(lane, LR);
  const float d0r = hl ? u[6] : u[0], d0i = hl ? u[7] : u[1];
  const float o0r = hl ? u[4] : u[2], o0i = hl ? u[5] : u[3];
  const float d1r = hl ? u[0] : u[6], d1i = hl ? u[1] : u[7];
  const float o1r = hl ? u[2] : u[4], o1i = hl ? u[3] : u[5];
  if constexpr (LM != 0) {
    float tr[8], ti[8];
    #pragma unroll
    for (int s = 0; s < 8; ++s) {
      tr[s] = __shfl_xor(pr[s ^ SM], LM);
      ti[s] = __shfl_xor(pi[s ^ SM], LM);
    }
    #pragma unroll
    for (int s = 0; s < 8; ++s) {
      const bool c1 = cpar3(s & SR);
      const float dr = c1 ? d1r : d0r, di = c1 ? d1i : d0i;
      const float orr = c1 ? o1r : o0r, oi = c1 ? o1i : o0i;
      float ar = pr[s], ai = pi[s];
      pr[s] = dr*ar - di*ai + orr*tr[s] - oi*ti[s];
      pi[s] = dr*ai + di*ar + orr*ti[s] + oi*tr[s];
    }
  } else {
    constexpr int LOW = SM & (-SM);
    #pragma unroll
    for (int s = 0; s < 8; ++s) if (!(s & LOW)) {
      const int s1 = s ^ SM;
      const bool c1 = cpar3(s & SR);
      const float dAr = c1 ? d1r : d0r, dAi = c1 ? d1i : d0i;
      const float oAr = c1 ? o1r : o0r, oAi = c1 ? o1i : o0i;
      const float dBr = c1 ? d0r : d1r, dBi = c1 ? d0i : d1i;
      const float oBr = c1 ? o0r : o1r, oBi = c1 ? o0i : o1i;
      float ar = pr[s], ai = pi[s], br = pr[s1], bi = pi[s1];
      pr[s]  = dAr*ar - dAi*ai + oAr*br - oAi*bi;
      pi[s]  = dAr*ai + dAi*ar + oAr*bi + oAi*br;
      pr[s1] = dBr*br - dBi*bi + oBr*ar - oBi*ai;
      pi[s1] = dBr*bi + dBi*br + oBr*ai + oBi*ar;
    }
  }
}

// ---- general 4x4 two-qubit gate, 2-gather decomposition -------------------
#define U4CLASS(Q)                                                            \
  if constexpr (!(((SRc == 0) && (Q & 2)) || ((SRt == 0) && (Q & 1)))) {      \
    const int r1 = R ^ Q, r2 = r1 ^ 2;                                        \
    const float2 wd = w2[r1 * 4 + r1],       wo = w2[r1 * 4 + (r1 ^ 1)];      \
    const float2 vd = w2[r2 * 4 + r1],       vo = w2[r2 * 4 + (r1 ^ 1)];      \
    _Pragma("unroll")                                                         \
    for (int s = 0; s < 8; ++s)                                               \
      if (((cpar3(s & SRc) << 1) | cpar3(s & SRt)) == Q) {                    \
        float ar = pr[s], ai = pi[s], br = tr[s], bi = ti[s];                 \
        pr[s] = wd.x*ar - wd.y*ai + wo.x*br - wo.y*bi;                        \
        pi[s] = wd.x*ai + wd.y*ar + wo.x*bi + wo.y*br;                        \
        tr[s] = vd.x*ar - vd.y*ai + vo.x*br - vo.y*bi;                        \
        ti[s] = vd.x*ai + vd.y*ar + vo.x*bi + vo.y*br;                        \
      }                                                                       \
  }

template<int LMc, int SMc, int LMt, int SMt, int LRc, int SRc, int LRt, int SRt>
DEV void u4_g(float* pr, float* pi, const float2* w2, int lane) {
  const int R = (lpar(lane, LRc) << 1) | lpar(lane, LRt);
  float tr[8], ti[8];
  #pragma unroll
  for (int s = 0; s < 8; ++s) {
    float vr = pr[s ^ SMt], vi = pi[s ^ SMt];
    if constexpr (LMt != 0) { vr = __shfl_xor(vr, LMt); vi = __shfl_xor(vi, LMt); }
    tr[s] = vr; ti[s] = vi;
  }
  U4CLASS(0) U4CLASS(1) U4CLASS(2) U4CLASS(3)
  #pragma unroll
  for (int s = 0; s < 8; ++s) {
    float br = tr[s ^ SMc], bi = ti[s ^ SMc];
    if constexpr (LMc != 0) { br = __shfl_xor(br, LMc); bi = __shfl_xor(bi, LMc); }
    pr[s] += br; pi[s] += bi;
  }
}

// ---- U3 coefficient build -------------------------------------------------
DEV void u3_make(float t, float p, float l, float* u) {
  float c = __cosf(0.5f * t), s = __sinf(0.5f * t);
  float cp = __cosf(p), sp = __sinf(p);
  float cl = __cosf(l), sl = __sinf(l);
  float cpl = __cosf(p + l), spl = __sinf(p + l);
  u[0] = c;        u[1] = 0.0f;
  u[2] = -cl * s;  u[3] = -sl * s;
  u[4] = cp * s;   u[5] = sp * s;
  u[6] = cpl * c;  u[7] = spl * c;
}

// ---- <Z3>,<Z7>: r3 = (LR=20,SR=1), r7 = (LR=20,SR=0); 32-lane reduce ------
DEV void expz_fin(const float* pr, const float* pi, int lane, float& z3, float& z7) {
  float t3 = 0.0f, t7 = 0.0f;
  #pragma unroll
  for (int s = 0; s < 8; ++s) {
    float p = pr[s] * pr[s] + pi[s] * pi[s];
    t7 += p;
    t3 += (s & 1) ? -p : p;
  }
  if (lpar(lane, 20)) { t3 = -t3; t7 = -t7; }
  #pragma unroll
  for (int m = 1; m < 32; m <<= 1) {
    t3 += __shfl_xor(t3, m);
    t7 += __shfl_xor(t7, m);
  }
  z3 = t3; z7 = t7;
}

// ---------------------------------------------------------------------------

__global__ __launch_bounds__(256, 2)
void qcnn_kernel(const float* __restrict__ x,
                 const float* __restrict__ rz_p, const float* __restrict__ ry_p,
                 const float* __restrict__ ry2_p, const float* __restrict__ crx_p,
                 const float* __restrict__ u3_p, const float* __restrict__ u3b_p,
                 const float* __restrict__ W1, const float* __restrict__ b1,
                 const float* __restrict__ W2, const float* __restrict__ b2,
                 float* __restrict__ out, int B) {
  // cw: [layer][type][16 complex]  (type 0 = fused conv U4, 1 = CRX-as-4x4)
  __shared__ __align__(8) float cw[128];

  const int tid  = threadIdx.x;
  const int lane = tid & 63;
  const int wave = tid >> 6;
  const int l5   = lane & 31;
  const int hb   = lane & 32;
  const int elem = blockIdx.x * 8 + wave * 2 + (lane >> 5);
  const int elemc = elem < B ? elem : (B - 1);

  // ---- weight build (wave 0): lanes 0..31 conv-U4, lanes 32..63 CRX -------
  if (tid < 32) {
    const int lay = tid >> 4, e = tid & 15, i4 = e >> 2, j4 = e & 3;
    const int base = tid & 48;
    const float c45 = 0.70710678118654752f;
    float rz = rz_p[lay], ry = ry_p[lay], ry2 = ry2_p[lay];
    float mr = (i4 == j4) ? c45 : 0.0f;
    float mi = (i4 == j4) ? ((i4 & 1) ? -c45 : c45) : 0.0f;
    { int t = (i4 & 1) ? (i4 ^ 2) : i4; int src = base | (t << 2) | j4;
      mr = __shfl(mr, src); mi = __shfl(mi, src); }
    { float cz = __cosf(0.5f * rz), sz = __sinf(0.5f * rz);
      float di = (i4 & 2) ? sz : -sz;
      float nr = cz * mr - di * mi, ni = cz * mi + di * mr; mr = nr; mi = ni; }
    { float cy = __cosf(0.5f * ry), sy = __sinf(0.5f * ry);
      int src = base | ((i4 ^ 1) << 2) | j4;
      float orr = __shfl(mr, src), oii = __shfl(mi, src);
      float sg = (i4 & 1) ? sy : -sy;
      mr = cy * mr + sg * orr; mi = cy * mi + sg * oii; }
    { int t = (i4 & 2) ? (i4 ^ 1) : i4; int src = base | (t << 2) | j4;
      mr = __shfl(mr, src); mi = __shfl(mi, src); }
    { float cy = __cosf(0.5f * ry2), sy = __sinf(0.5f * ry2);
      int src = base | ((i4 ^ 1) << 2) | j4;
      float orr = __shfl(mr, src), oii = __shfl(mi, src);
      float sg = (i4 & 1) ? sy : -sy;
      mr = cy * mr + sg * orr; mi = cy * mi + sg * oii; }
    { int t = (i4 & 1) ? (i4 ^ 2) : i4; int src = base | (t << 2) | j4;
      mr = __shfl(mr, src); mi = __shfl(mi, src); }
    { float di = (i4 & 2) ? c45 : -c45;
      float nr = c45 * mr - di * mi, ni = c45 * mi + di * mr; mr = nr; mi = ni; }
    cw[((lay * 2 + 0) * 16 + e) * 2]     = mr;
    cw[((lay * 2 + 0) * 16 + e) * 2 + 1] = mi;
  } else if (tid < 64) {
    const int t2 = tid - 32;
    const int lay = t2 >> 4, e = t2 & 15, i4 = e >> 2, j4 = e & 3;
    float t = crx_p[lay];
    float c = __cosf(0.5f * t), s = __sinf(0.5f * t);
    float mr = 0.0f, mi = 0.0f;
    if (i4 == j4) mr = (i4 < 2) ? 1.0f : c;
    if ((i4 >= 2) && ((i4 ^ j4) == 1)) mi = -s;
    cw[((lay * 2 + 1) * 16 + e) * 2]     = mr;
    cw[((lay * 2 + 1) * 16 + e) * 2 + 1] = mi;
  }

  // ---- angles: lane l5 holds angle l5 of its element ----------------------
  float a0 = x[(size_t)elemc * 32 + l5];
  float ch = __cosf(0.5f * a0), sh = __sinf(0.5f * a0);

  // cycle-1 angle broadcasts (angles 0..7)
  float cq[8], sq[8];
  #pragma unroll
  for (int q = 0; q < 8; ++q) {
    cq[q] = __shfl(ch, hb | q);
    sq[q] = __shfl(sh, hb | q);
  }

  // ---- product-state init (cycle-1 RYs; state real) -----------------------
  // l5 bits 4..0 = q0,q2,q4,q6,q1 ; s bits 2..0 = q3,q5,q7
  float p[8];
  {
    float g = ((l5 & 16) ? sq[0] : cq[0]) * ((l5 & 8) ? sq[2] : cq[2]) *
              ((l5 & 4)  ? sq[4] : cq[4]) * ((l5 & 2) ? sq[6] : cq[6]) *
              ((l5 & 1)  ? sq[1] : cq[1]);
    #pragma unroll
    for (int s = 0; s < 8; ++s)
      p[s] = g * ((s & 4) ? sq[3] : cq[3]) * ((s & 2) ? sq[5] : cq[5]) *
                 ((s & 1) ? sq[7] : cq[7]);
  }

  // ---- encode cycles 2..4 (24 real RYs; masks = R6 masks via bit-move) ----
  #define ENC(k, LM, SM, LR, SR) {                 \
    float gc = __shfl(ch, hb | (k));               \
    float gs = __shfl(sh, hb | (k));               \
    ryr<LM, SM, LR, SR>(p, gc, gs, lane); }

  ENC(8,  17,0, 15,7)  ENC(9,  9,0,  17,0)  ENC(10, 8,4,  25,0)  ENC(11, 4,4,  25,4)
  ENC(12, 4,2,  29,4)  ENC(13, 2,2,  29,6)  ENC(14, 2,1,  31,6)  ENC(15, 17,1, 31,7)
  ENC(16, 24,0, 17,7)  ENC(17, 1,4,  30,7)  ENC(18, 12,0, 7,7)   ENC(19, 0,6,  30,3)
  ENC(20, 6,0,  3,7)   ENC(21, 0,3,  30,1)  ENC(22, 19,0, 1,7)   ENC(23, 9,1,  30,0)
  ENC(24, 25,4, 5,2)   ENC(25, 13,4, 15,0)  ENC(26, 12,6, 8,7)   ENC(27, 6,6,  22,4)
  ENC(28, 6,3,  21,3)  ENC(29, 19,3, 11,2)  ENC(30, 26,1, 10,5)  ENC(31, 16,5, 20,5)
  #undef ENC

  // park encoded (real) state in VGPRs
  float enc[8];
  #pragma unroll
  for (int s = 0; s < 8; ++s) enc[s] = p[s];

  __syncthreads();  // cw ready

  float fz3[2], fz7[2];

  #pragma unroll 1
  for (int it = 0; it < 2; ++it) {
    const float2* wL0 = ((const float2*)cw) + (0 * 2 + it) * 16;
    const float2* wL1 = ((const float2*)cw) + (1 * 2 + it) * 16;
    const float* u3src = it ? u3b_p : u3_p;

    float pi_[8];
    #pragma unroll
    for (int s = 0; s < 8; ++s) { p[s] = enc[s]; pi_[s] = 0.0f; }

    // layer 0: pairs (0,1)(2,3)(4,5)(6,7)(1,2)(3,4)(5,6)
    u4_g<20,0, 1,2,  17,2, 10,2>(p, pi_, wL0, lane);   // (0,1)
    u4_g<10,0, 0,5,  2,5,  20,1>(p, pi_, wL0, lane);   // (2,3)
    u4_g<21,0, 9,2,  1,2,  10,0>(p, pi_, wL0, lane);   // (4,5)
    u4_g<10,4, 4,5,  0,5,  20,0>(p, pi_, wL0, lane);   // (6,7)
    u4_g<1,2,  10,0, 10,2, 2,5 >(p, pi_, wL0, lane);   // (1,2)
    u4_g<0,5,  21,0, 20,1, 1,2 >(p, pi_, wL0, lane);   // (3,4)
    u4_g<9,2,  10,4, 10,0, 0,5 >(p, pi_, wL0, lane);   // (5,6)
    {
      float us[8]; u3_make(u3src[0], u3src[1], u3src[2], us);
      u3_g<1,2, 10,2>(p, pi_, us, lane);   // q1
      u3_g<0,5, 20,1>(p, pi_, us, lane);   // q3
      u3_g<9,2, 10,0>(p, pi_, us, lane);   // q5
      u3_g<4,5, 20,0>(p, pi_, us, lane);   // q7
    }
    // layer 1: pairs (1,3)(5,7)(3,5)
    u4_g<1,2,  0,5,  10,2, 20,1>(p, pi_, wL1, lane);   // (1,3)
    u4_g<9,2,  4,5,  10,0, 20,0>(p, pi_, wL1, lane);   // (5,7)
    u4_g<0,5,  9,2,  20,1, 10,0>(p, pi_, wL1, lane);   // (3,5)
    {
      float us[8]; u3_make(u3src[3], u3src[4], u3src[5], us);
      u3_g<0,5, 20,1>(p, pi_, us, lane);   // q3
      u3_g<4,5, 20,0>(p, pi_, us, lane);   // q7
    }

    expz_fin(p, pi_, lane, fz3[it], fz7[it]);
  }

  // ---- MLP: lane j (=l5, j<15) computes hidden unit j ---------------------
  const int j = (l5 < 15) ? l5 : 0;
  float acc = W1[j * 4 + 0] * fz3[0] + W1[j * 4 + 1] * fz7[0] +
              W1[j * 4 + 2] * fz3[1] + W1[j * 4 + 3] * fz7[1] + b1[j];
  float e2 = __expf(2.0f * acc);
  float th = (e2 - 1.0f) / (e2 + 1.0f);
  float part = (l5 < 15) ? th * W2[j] : 0.0f;
  #pragma unroll
  for (int m = 1; m < 32; m <<= 1) part += __shfl_xor(part, m);

  if (l5 == 0 && elem < B) {
    float z = part + b2[0];
    out[elem] = 1.0f / (1.0f + __expf(-z));
  }
}

extern "C" void kernel_launch(void* const* d_in, const int* in_sizes, int n_in,
                              void* d_out, int out_size, void* d_ws, size_t ws_size,
                              hipStream_t stream) {
  (void)n_in; (void)out_size; (void)d_ws; (void)ws_size;
  const float* x     = (const float*)d_in[0];
  const float* rz_p  = (const float*)d_in[1];
  const float* ry_p  = (const float*)d_in[2];
  const float* ry2_p = (const float*)d_in[3];
  const float* crx_p = (const float*)d_in[4];
  const float* u3_p  = (const float*)d_in[5];
  const float* u3b_p = (const float*)d_in[6];
  const float* W1    = (const float*)d_in[7];
  const float* b1    = (const float*)d_in[8];
  const float* W2    = (const float*)d_in[9];
  const float* b2    = (const float*)d_in[10];
  float* out = (float*)d_out;

  const int B = in_sizes[0] / 32;          // 8192
  const int blocks = (B + 7) / 8;          // 2 elems/wave, 4 waves/block
  qcnn_kernel<<<dim3(blocks), dim3(256), 0, stream>>>(
      x, rz_p, ry_p, ry2_p, crx_p, u3_p, u3b_p, W1, b1, W2, b2, out, B);
}

// Round 9
// 118.722 us; speedup vs baseline: 1.1490x; 1.1196x over previous
//
#include <hip/hip_runtime.h>

#define DEV __device__ __forceinline__

// ---------------------------------------------------------------------------
// R9 = R8's layout (32 lanes/element, 8 amps/lane, 4096 waves = 4 waves/SIMD,
// masks correctness-verified by R8's pass) with R6's SPARSE CRX path restored.
// R8's mistake: psi1's CRX ladder ran through the dense u4_g (~18 VALU/slot);
// sparse crx_g is ~4 VALU/slot. CRX masks = each u4's (LMt,SMt, LRc,SRc);
// invariant <target-mask, control-parity> = 0 verified for all 10 gates.
// Index: j = (l5<<3)|s, l5 = lane&31, s in [0,8).
//   l5 bits 4..0 = q0,q2,q4,q6,q1 ; s bits 2..0 = q3,q5,q7.
// __launch_bounds__(256,2): only bound observed to give spill-free alloc.
// ---------------------------------------------------------------------------

DEV int lpar(int lane, int m) { return __builtin_popcount(lane & m) & 1; }
constexpr int cpar3(int v) { return (v ^ (v >> 1) ^ (v >> 2)) & 1; }

// ---- real RY with general pair mask / parity ------------------------------
template<int LM, int SM, int LR, int SR>
DEV void ryr(float* p, float gc, float gs, int lane) {
  const float sg0 = lpar(lane, LR) ? gs : -gs;   // sign when cpar3(s&SR)==0
  const float sg1 = -sg0;
  if constexpr (LM != 0) {
    float t[8];
    #pragma unroll
    for (int s = 0; s < 8; ++s) t[s] = __shfl_xor(p[s ^ SM], LM);
    #pragma unroll
    for (int s = 0; s < 8; ++s)
      p[s] = gc * p[s] + (cpar3(s & SR) ? sg1 : sg0) * t[s];
  } else {
    constexpr int LOW = SM & (-SM);
    #pragma unroll
    for (int s = 0; s < 8; ++s) if (!(s & LOW)) {
      const int s1 = s ^ SM;
      float a = p[s], b = p[s1];
      float sg = cpar3(s & SR) ? sg1 : sg0;
      p[s]  = gc * a + sg * b;
      p[s1] = gc * b - sg * a;
    }
  }
}

// ---- complex U3: u[8] = {u00r,u00i,u01r,u01i,u10r,u10i,u11r,u11i} --------
template<int LM, int SM, int LR, int SR>
DEV void u3_g(float* pr, float* pi, const float* u, int lane) {
  const bool hl = lpar(lane, LR);
  const float d0r = hl ? u[6] : u[0], d0i = hl ? u[7] : u[1];
  const float o0r = hl ? u[4] : u[2], o0i = hl ? u[5] : u[3];
  const float d1r = hl ? u[0] : u[6], d1i = hl ? u[1] : u[7];
  const float o1r = hl ? u[2] : u[4], o1i = hl ? u[3] : u[5];
  if constexpr (LM != 0) {
    float tr[8], ti[8];
    #pragma unroll
    for (int s = 0; s < 8; ++s) {
      tr[s] = __shfl_xor(pr[s ^ SM], LM);
      ti[s] = __shfl_xor(pi[s ^ SM], LM);
    }
    #pragma unroll
    for (int s = 0; s < 8; ++s) {
      const bool c1 = cpar3(s & SR);
      const float dr = c1 ? d1r : d0r, di = c1 ? d1i : d0i;
      const float orr = c1 ? o1r : o0r, oi = c1 ? o1i : o0i;
      float ar = pr[s], ai = pi[s];
      pr[s] = dr*ar - di*ai + orr*tr[s] - oi*ti[s];
      pi[s] = dr*ai + di*ar + orr*ti[s] + oi*tr[s];
    }
  } else {
    constexpr int LOW = SM & (-SM);
    #pragma unroll
    for (int s = 0; s < 8; ++s) if (!(s & LOW)) {
      const int s1 = s ^ SM;
      const bool c1 = cpar3(s & SR);
      const float dAr = c1 ? d1r : d0r, dAi = c1 ? d1i : d0i;
      const float oAr = c1 ? o1r : o0r, oAi = c1 ? o1i : o0i;
      const float dBr = c1 ? d0r : d1r, dBi = c1 ? d0i : d1i;
      const float oBr = c1 ? o0r : o1r, oBi = c1 ? o0i : o1i;
      float ar = pr[s], ai = pi[s], br = pr[s1], bi = pi[s1];
      pr[s]  = dAr*ar - dAi*ai + oAr*br - oAi*bi;
      pi[s]  = dAr*ai + dAi*ar + oAr*bi + oAi*br;
      pr[s1] = dBr*br - dBi*bi + oBr*ar - oBi*ai;
      pi[s1] = dBr*bi + dBi*br + oBr*ai + oBi*ar;
    }
  }
}

// ---- sparse CRX: target pair mask (LMt,SMt), control parity (LRc,SRc) -----
// Valid because <(LMt,SMt),(LRc,SRc)> = 0 for every gate (checked).
template<int LMt, int SMt, int LRc, int SRc>
DEV void crx_g(float* pr, float* pi, float c, float s_, int lane) {
  const bool hl = lpar(lane, LRc);
  const float cc0 = hl ? c : 1.0f, ss0 = hl ? s_ : 0.0f;   // class cpar3==0
  const float cc1 = hl ? 1.0f : c, ss1 = hl ? 0.0f : s_;   // class cpar3==1
  if constexpr (LMt != 0) {
    float tr[8], ti[8];
    #pragma unroll
    for (int s = 0; s < 8; ++s) {
      tr[s] = __shfl_xor(pr[s ^ SMt], LMt);
      ti[s] = __shfl_xor(pi[s ^ SMt], LMt);
    }
    #pragma unroll
    for (int s = 0; s < 8; ++s) {
      const bool c1 = cpar3(s & SRc);
      const float cc = c1 ? cc1 : cc0, ss = c1 ? ss1 : ss0;
      float ar = pr[s], ai = pi[s];
      pr[s] = cc * ar + ss * ti[s];
      pi[s] = cc * ai - ss * tr[s];
    }
  } else {
    constexpr int LOW = SMt & (-SMt);
    #pragma unroll
    for (int s = 0; s < 8; ++s) if (!(s & LOW)) {
      const int s1 = s ^ SMt;
      const bool c1 = cpar3(s & SRc);
      const float cc = c1 ? cc1 : cc0, ss = c1 ? ss1 : ss0;
      float ar = pr[s], ai = pi[s], br = pr[s1], bi = pi[s1];
      pr[s]  = cc * ar + ss * bi;
      pi[s]  = cc * ai - ss * br;
      pr[s1] = cc * br + ss * ai;
      pi[s1] = cc * bi - ss * ar;
    }
  }
}

// ---- general 4x4 two-qubit gate, 2-gather decomposition -------------------
#define U4CLASS(Q)                                                            \
  if constexpr (!(((SRc == 0) && (Q & 2)) || ((SRt == 0) && (Q & 1)))) {      \
    const int r1 = R ^ Q, r2 = r1 ^ 2;                                        \
    const float2 wd = w2[r1 * 4 + r1],       wo = w2[r1 * 4 + (r1 ^ 1)];      \
    const float2 vd = w2[r2 * 4 + r1],       vo = w2[r2 * 4 + (r1 ^ 1)];      \
    _Pragma("unroll")                                                         \
    for (int s = 0; s < 8; ++s)                                               \
      if (((cpar3(s & SRc) << 1) | cpar3(s & SRt)) == Q) {                    \
        float ar = pr[s], ai = pi[s], br = tr[s], bi = ti[s];                 \
        pr[s] = wd.x*ar - wd.y*ai + wo.x*br - wo.y*bi;                        \
        pi[s] = wd.x*ai + wd.y*ar + wo.x*bi + wo.y*br;                        \
        tr[s] = vd.x*ar - vd.y*ai + vo.x*br - vo.y*bi;                        \
        ti[s] = vd.x*ai + vd.y*ar + vo.x*bi + vo.y*br;                        \
      }                                                                       \
  }

template<int LMc, int SMc, int LMt, int SMt, int LRc, int SRc, int LRt, int SRt>
DEV void u4_g(float* pr, float* pi, const float2* w2, int lane) {
  const int R = (lpar(lane, LRc) << 1) | lpar(lane, LRt);
  float tr[8], ti[8];
  #pragma unroll
  for (int s = 0; s < 8; ++s) {
    float vr = pr[s ^ SMt], vi = pi[s ^ SMt];
    if constexpr (LMt != 0) { vr = __shfl_xor(vr, LMt); vi = __shfl_xor(vi, LMt); }
    tr[s] = vr; ti[s] = vi;
  }
  U4CLASS(0) U4CLASS(1) U4CLASS(2) U4CLASS(3)
  #pragma unroll
  for (int s = 0; s < 8; ++s) {
    float br = tr[s ^ SMc], bi = ti[s ^ SMc];
    if constexpr (LMc != 0) { br = __shfl_xor(br, LMc); bi = __shfl_xor(bi, LMc); }
    pr[s] += br; pi[s] += bi;
  }
}

// ---- U3 coefficient build -------------------------------------------------
DEV void u3_make(float t, float p, float l, float* u) {
  float c = __cosf(0.5f * t), s = __sinf(0.5f * t);
  float cp = __cosf(p), sp = __sinf(p);
  float cl = __cosf(l), sl = __sinf(l);
  float cpl = __cosf(p + l), spl = __sinf(p + l);
  u[0] = c;        u[1] = 0.0f;
  u[2] = -cl * s;  u[3] = -sl * s;
  u[4] = cp * s;   u[5] = sp * s;
  u[6] = cpl * c;  u[7] = spl * c;
}

// ---- <Z3>,<Z7>: r3 = (LR=20,SR=1), r7 = (LR=20,SR=0); 32-lane reduce ------
DEV void expz_fin(const float* pr, const float* pi, int lane, float& z3, float& z7) {
  float t3 = 0.0f, t7 = 0.0f;
  #pragma unroll
  for (int s = 0; s < 8; ++s) {
    float p = pr[s] * pr[s] + pi[s] * pi[s];
    t7 += p;
    t3 += (s & 1) ? -p : p;
  }
  if (lpar(lane, 20)) { t3 = -t3; t7 = -t7; }
  #pragma unroll
  for (int m = 1; m < 32; m <<= 1) {
    t3 += __shfl_xor(t3, m);
    t7 += __shfl_xor(t7, m);
  }
  z3 = t3; z7 = t7;
}

// ---------------------------------------------------------------------------

__global__ __launch_bounds__(256, 2)
void qcnn_kernel(const float* __restrict__ x,
                 const float* __restrict__ rz_p, const float* __restrict__ ry_p,
                 const float* __restrict__ ry2_p, const float* __restrict__ crx_p,
                 const float* __restrict__ u3_p, const float* __restrict__ u3b_p,
                 const float* __restrict__ W1, const float* __restrict__ b1,
                 const float* __restrict__ W2, const float* __restrict__ b2,
                 float* __restrict__ out, int B) {
  __shared__ __align__(8) float cw[64];   // 2 layers x 16 complex fused conv-U4

  const int tid  = threadIdx.x;
  const int lane = tid & 63;
  const int wave = tid >> 6;
  const int l5   = lane & 31;
  const int hb   = lane & 32;
  const int elem = blockIdx.x * 8 + wave * 2 + (lane >> 5);
  const int elemc = elem < B ? elem : (B - 1);

  // ---- fused conv-U4 build (wave 0, lanes 0..31) --------------------------
  if (tid < 32) {
    const int lay = tid >> 4, e = tid & 15, i4 = e >> 2, j4 = e & 3;
    const int base = tid & 48;
    const float c45 = 0.70710678118654752f;
    float rz = rz_p[lay], ry = ry_p[lay], ry2 = ry2_p[lay];
    float mr = (i4 == j4) ? c45 : 0.0f;
    float mi = (i4 == j4) ? ((i4 & 1) ? -c45 : c45) : 0.0f;
    { int t = (i4 & 1) ? (i4 ^ 2) : i4; int src = base | (t << 2) | j4;
      mr = __shfl(mr, src); mi = __shfl(mi, src); }
    { float cz = __cosf(0.5f * rz), sz = __sinf(0.5f * rz);
      float di = (i4 & 2) ? sz : -sz;
      float nr = cz * mr - di * mi, ni = cz * mi + di * mr; mr = nr; mi = ni; }
    { float cy = __cosf(0.5f * ry), sy = __sinf(0.5f * ry);
      int src = base | ((i4 ^ 1) << 2) | j4;
      float orr = __shfl(mr, src), oii = __shfl(mi, src);
      float sg = (i4 & 1) ? sy : -sy;
      mr = cy * mr + sg * orr; mi = cy * mi + sg * oii; }
    { int t = (i4 & 2) ? (i4 ^ 1) : i4; int src = base | (t << 2) | j4;
      mr = __shfl(mr, src); mi = __shfl(mi, src); }
    { float cy = __cosf(0.5f * ry2), sy = __sinf(0.5f * ry2);
      int src = base | ((i4 ^ 1) << 2) | j4;
      float orr = __shfl(mr, src), oii = __shfl(mi, src);
      float sg = (i4 & 1) ? sy : -sy;
      mr = cy * mr + sg * orr; mi = cy * mi + sg * oii; }
    { int t = (i4 & 1) ? (i4 ^ 2) : i4; int src = base | (t << 2) | j4;
      mr = __shfl(mr, src); mi = __shfl(mi, src); }
    { float di = (i4 & 2) ? c45 : -c45;
      float nr = c45 * mr - di * mi, ni = c45 * mi + di * mr; mr = nr; mi = ni; }
    cw[(lay * 16 + e) * 2]     = mr;
    cw[(lay * 16 + e) * 2 + 1] = mi;
  }

  // ---- angles: lane l5 holds angle l5 of its element ----------------------
  float a0 = x[(size_t)elemc * 32 + l5];
  float ch = __cosf(0.5f * a0), sh = __sinf(0.5f * a0);

  float cq[8], sq[8];
  #pragma unroll
  for (int q = 0; q < 8; ++q) {
    cq[q] = __shfl(ch, hb | q);
    sq[q] = __shfl(sh, hb | q);
  }

  // ---- product-state init (cycle-1 RYs; state real) -----------------------
  float p[8];
  {
    float g = ((l5 & 16) ? sq[0] : cq[0]) * ((l5 & 8) ? sq[2] : cq[2]) *
              ((l5 & 4)  ? sq[4] : cq[4]) * ((l5 & 2) ? sq[6] : cq[6]) *
              ((l5 & 1)  ? sq[1] : cq[1]);
    #pragma unroll
    for (int s = 0; s < 8; ++s)
      p[s] = g * ((s & 4) ? sq[3] : cq[3]) * ((s & 2) ? sq[5] : cq[5]) *
                 ((s & 1) ? sq[7] : cq[7]);
  }

  // ---- encode cycles 2..4 (24 real RYs; masks verified in R8) -------------
  #define ENC(k, LM, SM, LR, SR) {                 \
    float gc = __shfl(ch, hb | (k));               \
    float gs = __shfl(sh, hb | (k));               \
    ryr<LM, SM, LR, SR>(p, gc, gs, lane); }

  ENC(8,  17,0, 15,7)  ENC(9,  9,0,  17,0)  ENC(10, 8,4,  25,0)  ENC(11, 4,4,  25,4)
  ENC(12, 4,2,  29,4)  ENC(13, 2,2,  29,6)  ENC(14, 2,1,  31,6)  ENC(15, 17,1, 31,7)
  ENC(16, 24,0, 17,7)  ENC(17, 1,4,  30,7)  ENC(18, 12,0, 7,7)   ENC(19, 0,6,  30,3)
  ENC(20, 6,0,  3,7)   ENC(21, 0,3,  30,1)  ENC(22, 19,0, 1,7)   ENC(23, 9,1,  30,0)
  ENC(24, 25,4, 5,2)   ENC(25, 13,4, 15,0)  ENC(26, 12,6, 8,7)   ENC(27, 6,6,  22,4)
  ENC(28, 6,3,  21,3)  ENC(29, 19,3, 11,2)  ENC(30, 26,1, 10,5)  ENC(31, 16,5, 20,5)
  #undef ENC

  // park encoded (real) state in VGPRs
  float enc[8];
  #pragma unroll
  for (int s = 0; s < 8; ++s) enc[s] = p[s];

  __syncthreads();  // cw ready
  const float2* w0 = ((const float2*)cw);
  const float2* w1 = ((const float2*)cw) + 16;

  // ================= psi0: conv chain (dense fused U4) =====================
  float pi_[8];
  #pragma unroll
  for (int s = 0; s < 8; ++s) pi_[s] = 0.0f;

  u4_g<20,0, 1,2,  17,2, 10,2>(p, pi_, w0, lane);   // (0,1)
  u4_g<10,0, 0,5,  2,5,  20,1>(p, pi_, w0, lane);   // (2,3)
  u4_g<21,0, 9,2,  1,2,  10,0>(p, pi_, w0, lane);   // (4,5)
  u4_g<10,4, 4,5,  0,5,  20,0>(p, pi_, w0, lane);   // (6,7)
  u4_g<1,2,  10,0, 10,2, 2,5 >(p, pi_, w0, lane);   // (1,2)
  u4_g<0,5,  21,0, 20,1, 1,2 >(p, pi_, w0, lane);   // (3,4)
  u4_g<9,2,  10,4, 10,0, 0,5 >(p, pi_, w0, lane);   // (5,6)
  {
    float us[8]; u3_make(u3_p[0], u3_p[1], u3_p[2], us);
    u3_g<1,2, 10,2>(p, pi_, us, lane);   // q1
    u3_g<0,5, 20,1>(p, pi_, us, lane);   // q3
    u3_g<9,2, 10,0>(p, pi_, us, lane);   // q5
    u3_g<4,5, 20,0>(p, pi_, us, lane);   // q7
  }
  u4_g<1,2,  0,5,  10,2, 20,1>(p, pi_, w1, lane);   // (1,3)
  u4_g<9,2,  4,5,  10,0, 20,0>(p, pi_, w1, lane);   // (5,7)
  u4_g<0,5,  9,2,  20,1, 10,0>(p, pi_, w1, lane);   // (3,5)
  {
    float us[8]; u3_make(u3_p[3], u3_p[4], u3_p[5], us);
    u3_g<0,5, 20,1>(p, pi_, us, lane);   // q3
    u3_g<4,5, 20,0>(p, pi_, us, lane);   // q7
  }

  float fz3_0, fz7_0;
  expz_fin(p, pi_, lane, fz3_0, fz7_0);

  // ================= psi1: sparse CRX chain ================================
  #pragma unroll
  for (int s = 0; s < 8; ++s) { p[s] = enc[s]; pi_[s] = 0.0f; }

  {
    float t = crx_p[0];
    float cc = __cosf(0.5f * t), ss = __sinf(0.5f * t);
    crx_g<1,2,  17,2>(p, pi_, cc, ss, lane);   // (0,1)
    crx_g<0,5,  2,5 >(p, pi_, cc, ss, lane);   // (2,3)
    crx_g<9,2,  1,2 >(p, pi_, cc, ss, lane);   // (4,5)
    crx_g<4,5,  0,5 >(p, pi_, cc, ss, lane);   // (6,7)
    crx_g<10,0, 10,2>(p, pi_, cc, ss, lane);   // (1,2)
    crx_g<21,0, 20,1>(p, pi_, cc, ss, lane);   // (3,4)
    crx_g<10,4, 10,0>(p, pi_, cc, ss, lane);   // (5,6)
  }
  {
    float us[8]; u3_make(u3b_p[0], u3b_p[1], u3b_p[2], us);
    u3_g<1,2, 10,2>(p, pi_, us, lane);   // q1
    u3_g<0,5, 20,1>(p, pi_, us, lane);   // q3
    u3_g<9,2, 10,0>(p, pi_, us, lane);   // q5
    u3_g<4,5, 20,0>(p, pi_, us, lane);   // q7
  }
  {
    float t = crx_p[1];
    float cc = __cosf(0.5f * t), ss = __sinf(0.5f * t);
    crx_g<0,5,  10,2>(p, pi_, cc, ss, lane);   // (1,3)
    crx_g<4,5,  10,0>(p, pi_, cc, ss, lane);   // (5,7)
    crx_g<9,2,  20,1>(p, pi_, cc, ss, lane);   // (3,5)
  }
  {
    float us[8]; u3_make(u3b_p[3], u3b_p[4], u3b_p[5], us);
    u3_g<0,5, 20,1>(p, pi_, us, lane);   // q3
    u3_g<4,5, 20,0>(p, pi_, us, lane);   // q7
  }

  float fz3_1, fz7_1;
  expz_fin(p, pi_, lane, fz3_1, fz7_1);

  // ---- MLP: lane j (=l5, j<15) computes hidden unit j ---------------------
  const int j = (l5 < 15) ? l5 : 0;
  float acc = W1[j * 4 + 0] * fz3_0 + W1[j * 4 + 1] * fz7_0 +
              W1[j * 4 + 2] * fz3_1 + W1[j * 4 + 3] * fz7_1 + b1[j];
  float e2 = __expf(2.0f * acc);
  float th = (e2 - 1.0f) / (e2 + 1.0f);
  float part = (l5 < 15) ? th * W2[j] : 0.0f;
  #pragma unroll
  for (int m = 1; m < 32; m <<= 1) part += __shfl_xor(part, m);

  if (l5 == 0 && elem < B) {
    float z = part + b2[0];
    out[elem] = 1.0f / (1.0f + __expf(-z));
  }
}

extern "C" void kernel_launch(void* const* d_in, const int* in_sizes, int n_in,
                              void* d_out, int out_size, void* d_ws, size_t ws_size,
                              hipStream_t stream) {
  (void)n_in; (void)out_size; (void)d_ws; (void)ws_size;
  const float* x     = (const float*)d_in[0];
  const float* rz_p  = (const float*)d_in[1];
  const float* ry_p  = (const float*)d_in[2];
  const float* ry2_p = (const float*)d_in[3];
  const float* crx_p = (const float*)d_in[4];
  const float* u3_p  = (const float*)d_in[5];
  const float* u3b_p = (const float*)d_in[6];
  const float* W1    = (const float*)d_in[7];
  const float* b1    = (const float*)d_in[8];
  const float* W2    = (const float*)d_in[9];
  const float* b2    = (const float*)d_in[10];
  float* out = (float*)d_out;

  const int B = in_sizes[0] / 32;          // 8192
  const int blocks = (B + 7) / 8;          // 2 elems/wave, 4 waves/block
  qcnn_kernel<<<dim3(blocks), dim3(256), 0, stream>>>(
      x, rz_p, ry_p, ry2_p, crx_p, u3_p, u3b_p, W1, b1, W2, b2, out, B);
}

// Round 10
// 115.228 us; speedup vs baseline: 1.1838x; 1.0303x over previous
//
#include <hip/hip_runtime.h>

#define DEV __device__ __forceinline__

// ---------------------------------------------------------------------------
// R10 = R9 (32 lanes/element, 8 amps/lane, lazy-CNOT masks verified, sparse
// CRX) + gate-by-gate INTERLEAVE of the independent psi0 (conv) and psi1
// (CRX) chains: two independent dependency streams per wave fill the
// shuffle-latency bubbles at gate boundaries (R9: VALUBusy 55%, stalls on
// lgkmcnt between dependent gates). R4's interleave failed at the 128-reg
// cap (16-lane layout, 2x live set); here live ~110 regs under (256,2)'s
// 256 cap -> no spill path.
// Index: j = (l5<<3)|s, l5 = lane&31, s in [0,8).
//   l5 bits 4..0 = q0,q2,q4,q6,q1 ; s bits 2..0 = q3,q5,q7.
// ---------------------------------------------------------------------------

DEV int lpar(int lane, int m) { return __builtin_popcount(lane & m) & 1; }
constexpr int cpar3(int v) { return (v ^ (v >> 1) ^ (v >> 2)) & 1; }

// ---- real RY with general pair mask / parity ------------------------------
template<int LM, int SM, int LR, int SR>
DEV void ryr(float* p, float gc, float gs, int lane) {
  const float sg0 = lpar(lane, LR) ? gs : -gs;
  const float sg1 = -sg0;
  if constexpr (LM != 0) {
    float t[8];
    #pragma unroll
    for (int s = 0; s < 8; ++s) t[s] = __shfl_xor(p[s ^ SM], LM);
    #pragma unroll
    for (int s = 0; s < 8; ++s)
      p[s] = gc * p[s] + (cpar3(s & SR) ? sg1 : sg0) * t[s];
  } else {
    constexpr int LOW = SM & (-SM);
    #pragma unroll
    for (int s = 0; s < 8; ++s) if (!(s & LOW)) {
      const int s1 = s ^ SM;
      float a = p[s], b = p[s1];
      float sg = cpar3(s & SR) ? sg1 : sg0;
      p[s]  = gc * a + sg * b;
      p[s1] = gc * b - sg * a;
    }
  }
}

// ---- complex U3: u[8] = {u00r,u00i,u01r,u01i,u10r,u10i,u11r,u11i} --------
template<int LM, int SM, int LR, int SR>
DEV void u3_g(float* pr, float* pi, const float* u, int lane) {
  const bool hl = lpar(lane, LR);
  const float d0r = hl ? u[6] : u[0], d0i = hl ? u[7] : u[1];
  const float o0r = hl ? u[4] : u[2], o0i = hl ? u[5] : u[3];
  const float d1r = hl ? u[0] : u[6], d1i = hl ? u[1] : u[7];
  const float o1r = hl ? u[2] : u[4], o1i = hl ? u[3] : u[5];
  if constexpr (LM != 0) {
    float tr[8], ti[8];
    #pragma unroll
    for (int s = 0; s < 8; ++s) {
      tr[s] = __shfl_xor(pr[s ^ SM], LM);
      ti[s] = __shfl_xor(pi[s ^ SM], LM);
    }
    #pragma unroll
    for (int s = 0; s < 8; ++s) {
      const bool c1 = cpar3(s & SR);
      const float dr = c1 ? d1r : d0r, di = c1 ? d1i : d0i;
      const float orr = c1 ? o1r : o0r, oi = c1 ? o1i : o0i;
      float ar = pr[s], ai = pi[s];
      pr[s] = dr*ar - di*ai + orr*tr[s] - oi*ti[s];
      pi[s] = dr*ai + di*ar + orr*ti[s] + oi*tr[s];
    }
  } else {
    constexpr int LOW = SM & (-SM);
    #pragma unroll
    for (int s = 0; s < 8; ++s) if (!(s & LOW)) {
      const int s1 = s ^ SM;
      const bool c1 = cpar3(s & SR);
      const float dAr = c1 ? d1r : d0r, dAi = c1 ? d1i : d0i;
      const float oAr = c1 ? o1r : o0r, oAi = c1 ? o1i : o0i;
      const float dBr = c1 ? d0r : d1r, dBi = c1 ? d0i : d1i;
      const float oBr = c1 ? o0r : o1r, oBi = c1 ? o0i : o1i;
      float ar = pr[s], ai = pi[s], br = pr[s1], bi = pi[s1];
      pr[s]  = dAr*ar - dAi*ai + oAr*br - oAi*bi;
      pi[s]  = dAr*ai + dAi*ar + oAr*bi + oAi*br;
      pr[s1] = dBr*br - dBi*bi + oBr*ar - oBi*ai;
      pi[s1] = dBr*bi + dBi*br + oBr*ai + oBi*ar;
    }
  }
}

// ---- sparse CRX: target pair mask (LMt,SMt), control parity (LRc,SRc) -----
template<int LMt, int SMt, int LRc, int SRc>
DEV void crx_g(float* pr, float* pi, float c, float s_, int lane) {
  const bool hl = lpar(lane, LRc);
  const float cc0 = hl ? c : 1.0f, ss0 = hl ? s_ : 0.0f;
  const float cc1 = hl ? 1.0f : c, ss1 = hl ? 0.0f : s_;
  if constexpr (LMt != 0) {
    float tr[8], ti[8];
    #pragma unroll
    for (int s = 0; s < 8; ++s) {
      tr[s] = __shfl_xor(pr[s ^ SMt], LMt);
      ti[s] = __shfl_xor(pi[s ^ SMt], LMt);
    }
    #pragma unroll
    for (int s = 0; s < 8; ++s) {
      const bool c1 = cpar3(s & SRc);
      const float cc = c1 ? cc1 : cc0, ss = c1 ? ss1 : ss0;
      float ar = pr[s], ai = pi[s];
      pr[s] = cc * ar + ss * ti[s];
      pi[s] = cc * ai - ss * tr[s];
    }
  } else {
    constexpr int LOW = SMt & (-SMt);
    #pragma unroll
    for (int s = 0; s < 8; ++s) if (!(s & LOW)) {
      const int s1 = s ^ SMt;
      const bool c1 = cpar3(s & SRc);
      const float cc = c1 ? cc1 : cc0, ss = c1 ? ss1 : ss0;
      float ar = pr[s], ai = pi[s], br = pr[s1], bi = pi[s1];
      pr[s]  = cc * ar + ss * bi;
      pi[s]  = cc * ai - ss * br;
      pr[s1] = cc * br + ss * ai;
      pi[s1] = cc * bi - ss * ar;
    }
  }
}

// ---- general 4x4 two-qubit gate, 2-gather decomposition -------------------
#define U4CLASS(Q)                                                            \
  if constexpr (!(((SRc == 0) && (Q & 2)) || ((SRt == 0) && (Q & 1)))) {      \
    const int r1 = R ^ Q, r2 = r1 ^ 2;                                        \
    const float2 wd = w2[r1 * 4 + r1],       wo = w2[r1 * 4 + (r1 ^ 1)];      \
    const float2 vd = w2[r2 * 4 + r1],       vo = w2[r2 * 4 + (r1 ^ 1)];      \
    _Pragma("unroll")                                                         \
    for (int s = 0; s < 8; ++s)                                               \
      if (((cpar3(s & SRc) << 1) | cpar3(s & SRt)) == Q) {                    \
        float ar = pr[s], ai = pi[s], br = tr[s], bi = ti[s];                 \
        pr[s] = wd.x*ar - wd.y*ai + wo.x*br - wo.y*bi;                        \
        pi[s] = wd.x*ai + wd.y*ar + wo.x*bi + wo.y*br;                        \
        tr[s] = vd.x*ar - vd.y*ai + vo.x*br - vo.y*bi;                        \
        ti[s] = vd.x*ai + vd.y*ar + vo.x*bi + vo.y*br;                        \
      }                                                                       \
  }

template<int LMc, int SMc, int LMt, int SMt, int LRc, int SRc, int LRt, int SRt>
DEV void u4_g(float* pr, float* pi, const float2* w2, int lane) {
  const int R = (lpar(lane, LRc) << 1) | lpar(lane, LRt);
  float tr[8], ti[8];
  #pragma unroll
  for (int s = 0; s < 8; ++s) {
    float vr = pr[s ^ SMt], vi = pi[s ^ SMt];
    if constexpr (LMt != 0) { vr = __shfl_xor(vr, LMt); vi = __shfl_xor(vi, LMt); }
    tr[s] = vr; ti[s] = vi;
  }
  U4CLASS(0) U4CLASS(1) U4CLASS(2) U4CLASS(3)
  #pragma unroll
  for (int s = 0; s < 8; ++s) {
    float br = tr[s ^ SMc], bi = ti[s ^ SMc];
    if constexpr (LMc != 0) { br = __shfl_xor(br, LMc); bi = __shfl_xor(bi, LMc); }
    pr[s] += br; pi[s] += bi;
  }
}

// ---- U3 coefficient build -------------------------------------------------
DEV void u3_make(float t, float p, float l, float* u) {
  float c = __cosf(0.5f * t), s = __sinf(0.5f * t);
  float cp = __cosf(p), sp = __sinf(p);
  float cl = __cosf(l), sl = __sinf(l);
  float cpl = __cosf(p + l), spl = __sinf(p + l);
  u[0] = c;        u[1] = 0.0f;
  u[2] = -cl * s;  u[3] = -sl * s;
  u[4] = cp * s;   u[5] = sp * s;
  u[6] = cpl * c;  u[7] = spl * c;
}

// ---- <Z3>,<Z7>: r3 = (LR=20,SR=1), r7 = (LR=20,SR=0); 32-lane reduce ------
DEV void expz_fin(const float* pr, const float* pi, int lane, float& z3, float& z7) {
  float t3 = 0.0f, t7 = 0.0f;
  #pragma unroll
  for (int s = 0; s < 8; ++s) {
    float p = pr[s] * pr[s] + pi[s] * pi[s];
    t7 += p;
    t3 += (s & 1) ? -p : p;
  }
  if (lpar(lane, 20)) { t3 = -t3; t7 = -t7; }
  #pragma unroll
  for (int m = 1; m < 32; m <<= 1) {
    t3 += __shfl_xor(t3, m);
    t7 += __shfl_xor(t7, m);
  }
  z3 = t3; z7 = t7;
}

// ---------------------------------------------------------------------------

__global__ __launch_bounds__(256, 2)
void qcnn_kernel(const float* __restrict__ x,
                 const float* __restrict__ rz_p, const float* __restrict__ ry_p,
                 const float* __restrict__ ry2_p, const float* __restrict__ crx_p,
                 const float* __restrict__ u3_p, const float* __restrict__ u3b_p,
                 const float* __restrict__ W1, const float* __restrict__ b1,
                 const float* __restrict__ W2, const float* __restrict__ b2,
                 float* __restrict__ out, int B) {
  __shared__ __align__(8) float cw[64];   // 2 layers x 16 complex fused conv-U4

  const int tid  = threadIdx.x;
  const int lane = tid & 63;
  const int wave = tid >> 6;
  const int l5   = lane & 31;
  const int hb   = lane & 32;
  const int elem = blockIdx.x * 8 + wave * 2 + (lane >> 5);
  const int elemc = elem < B ? elem : (B - 1);

  // ---- fused conv-U4 build (wave 0, lanes 0..31) --------------------------
  if (tid < 32) {
    const int lay = tid >> 4, e = tid & 15, i4 = e >> 2, j4 = e & 3;
    const int base = tid & 48;
    const float c45 = 0.70710678118654752f;
    float rz = rz_p[lay], ry = ry_p[lay], ry2 = ry2_p[lay];
    float mr = (i4 == j4) ? c45 : 0.0f;
    float mi = (i4 == j4) ? ((i4 & 1) ? -c45 : c45) : 0.0f;
    { int t = (i4 & 1) ? (i4 ^ 2) : i4; int src = base | (t << 2) | j4;
      mr = __shfl(mr, src); mi = __shfl(mi, src); }
    { float cz = __cosf(0.5f * rz), sz = __sinf(0.5f * rz);
      float di = (i4 & 2) ? sz : -sz;
      float nr = cz * mr - di * mi, ni = cz * mi + di * mr; mr = nr; mi = ni; }
    { float cy = __cosf(0.5f * ry), sy = __sinf(0.5f * ry);
      int src = base | ((i4 ^ 1) << 2) | j4;
      float orr = __shfl(mr, src), oii = __shfl(mi, src);
      float sg = (i4 & 1) ? sy : -sy;
      mr = cy * mr + sg * orr; mi = cy * mi + sg * oii; }
    { int t = (i4 & 2) ? (i4 ^ 1) : i4; int src = base | (t << 2) | j4;
      mr = __shfl(mr, src); mi = __shfl(mi, src); }
    { float cy = __cosf(0.5f * ry2), sy = __sinf(0.5f * ry2);
      int src = base | ((i4 ^ 1) << 2) | j4;
      float orr = __shfl(mr, src), oii = __shfl(mi, src);
      float sg = (i4 & 1) ? sy : -sy;
      mr = cy * mr + sg * orr; mi = cy * mi + sg * oii; }
    { int t = (i4 & 1) ? (i4 ^ 2) : i4; int src = base | (t << 2) | j4;
      mr = __shfl(mr, src); mi = __shfl(mi, src); }
    { float di = (i4 & 2) ? c45 : -c45;
      float nr = c45 * mr - di * mi, ni = c45 * mi + di * mr; mr = nr; mi = ni; }
    cw[(lay * 16 + e) * 2]     = mr;
    cw[(lay * 16 + e) * 2 + 1] = mi;
  }

  // ---- angles: lane l5 holds angle l5 of its element ----------------------
  float a0 = x[(size_t)elemc * 32 + l5];
  float ch = __cosf(0.5f * a0), sh = __sinf(0.5f * a0);

  float cq[8], sq[8];
  #pragma unroll
  for (int q = 0; q < 8; ++q) {
    cq[q] = __shfl(ch, hb | q);
    sq[q] = __shfl(sh, hb | q);
  }

  // ---- product-state init (cycle-1 RYs; state real) -----------------------
  float p[8];
  {
    float g = ((l5 & 16) ? sq[0] : cq[0]) * ((l5 & 8) ? sq[2] : cq[2]) *
              ((l5 & 4)  ? sq[4] : cq[4]) * ((l5 & 2) ? sq[6] : cq[6]) *
              ((l5 & 1)  ? sq[1] : cq[1]);
    #pragma unroll
    for (int s = 0; s < 8; ++s)
      p[s] = g * ((s & 4) ? sq[3] : cq[3]) * ((s & 2) ? sq[5] : cq[5]) *
                 ((s & 1) ? sq[7] : cq[7]);
  }

  // ---- encode cycles 2..4 (24 real RYs; masks verified in R8/R9) ----------
  #define ENC(k, LM, SM, LR, SR) {                 \
    float gc = __shfl(ch, hb | (k));               \
    float gs = __shfl(sh, hb | (k));               \
    ryr<LM, SM, LR, SR>(p, gc, gs, lane); }

  ENC(8,  17,0, 15,7)  ENC(9,  9,0,  17,0)  ENC(10, 8,4,  25,0)  ENC(11, 4,4,  25,4)
  ENC(12, 4,2,  29,4)  ENC(13, 2,2,  29,6)  ENC(14, 2,1,  31,6)  ENC(15, 17,1, 31,7)
  ENC(16, 24,0, 17,7)  ENC(17, 1,4,  30,7)  ENC(18, 12,0, 7,7)   ENC(19, 0,6,  30,3)
  ENC(20, 6,0,  3,7)   ENC(21, 0,3,  30,1)  ENC(22, 19,0, 1,7)   ENC(23, 9,1,  30,0)
  ENC(24, 25,4, 5,2)   ENC(25, 13,4, 15,0)  ENC(26, 12,6, 8,7)   ENC(27, 6,6,  22,4)
  ENC(28, 6,3,  21,3)  ENC(29, 19,3, 11,2)  ENC(30, 26,1, 10,5)  ENC(31, 16,5, 20,5)
  #undef ENC

  __syncthreads();  // cw ready
  const float2* w0 = ((const float2*)cw);
  const float2* w1 = ((const float2*)cw) + 16;

  // ---- two independent states, chains interleaved gate-by-gate ------------
  float p0[8], pi0[8], p1[8], pi1[8];
  #pragma unroll
  for (int s = 0; s < 8; ++s) {
    p0[s] = p[s]; pi0[s] = 0.0f;
    p1[s] = p[s]; pi1[s] = 0.0f;
  }

  float cc0, ss0, cc1, ss1;
  { float t = crx_p[0]; cc0 = __cosf(0.5f * t); ss0 = __sinf(0.5f * t); }
  { float t = crx_p[1]; cc1 = __cosf(0.5f * t); ss1 = __sinf(0.5f * t); }

  // layer 0: pairs (0,1)(2,3)(4,5)(6,7)(1,2)(3,4)(5,6)
  u4_g<20,0, 1,2,  17,2, 10,2>(p0, pi0, w0, lane);  crx_g<1,2,  17,2>(p1, pi1, cc0, ss0, lane);
  u4_g<10,0, 0,5,  2,5,  20,1>(p0, pi0, w0, lane);  crx_g<0,5,  2,5 >(p1, pi1, cc0, ss0, lane);
  u4_g<21,0, 9,2,  1,2,  10,0>(p0, pi0, w0, lane);  crx_g<9,2,  1,2 >(p1, pi1, cc0, ss0, lane);
  u4_g<10,4, 4,5,  0,5,  20,0>(p0, pi0, w0, lane);  crx_g<4,5,  0,5 >(p1, pi1, cc0, ss0, lane);
  u4_g<1,2,  10,0, 10,2, 2,5 >(p0, pi0, w0, lane);  crx_g<10,0, 10,2>(p1, pi1, cc0, ss0, lane);
  u4_g<0,5,  21,0, 20,1, 1,2 >(p0, pi0, w0, lane);  crx_g<21,0, 20,1>(p1, pi1, cc0, ss0, lane);
  u4_g<9,2,  10,4, 10,0, 0,5 >(p0, pi0, w0, lane);  crx_g<10,4, 10,0>(p1, pi1, cc0, ss0, lane);
  {
    float ua[8], ub[8];
    u3_make(u3_p[0], u3_p[1], u3_p[2], ua);
    u3_make(u3b_p[0], u3b_p[1], u3b_p[2], ub);
    u3_g<1,2, 10,2>(p0, pi0, ua, lane);  u3_g<1,2, 10,2>(p1, pi1, ub, lane);   // q1
    u3_g<0,5, 20,1>(p0, pi0, ua, lane);  u3_g<0,5, 20,1>(p1, pi1, ub, lane);   // q3
    u3_g<9,2, 10,0>(p0, pi0, ua, lane);  u3_g<9,2, 10,0>(p1, pi1, ub, lane);   // q5
    u3_g<4,5, 20,0>(p0, pi0, ua, lane);  u3_g<4,5, 20,0>(p1, pi1, ub, lane);   // q7
  }
  // layer 1: pairs (1,3)(5,7)(3,5)
  u4_g<1,2,  0,5,  10,2, 20,1>(p0, pi0, w1, lane);  crx_g<0,5,  10,2>(p1, pi1, cc1, ss1, lane);
  u4_g<9,2,  4,5,  10,0, 20,0>(p0, pi0, w1, lane);  crx_g<4,5,  10,0>(p1, pi1, cc1, ss1, lane);
  u4_g<0,5,  9,2,  20,1, 10,0>(p0, pi0, w1, lane);  crx_g<9,2,  20,1>(p1, pi1, cc1, ss1, lane);
  {
    float ua[8], ub[8];
    u3_make(u3_p[3], u3_p[4], u3_p[5], ua);
    u3_make(u3b_p[3], u3b_p[4], u3b_p[5], ub);
    u3_g<0,5, 20,1>(p0, pi0, ua, lane);  u3_g<0,5, 20,1>(p1, pi1, ub, lane);   // q3
    u3_g<4,5, 20,0>(p0, pi0, ua, lane);  u3_g<4,5, 20,0>(p1, pi1, ub, lane);   // q7
  }

  // ---- features -----------------------------------------------------------
  float fz3_0, fz7_0, fz3_1, fz7_1;
  expz_fin(p0, pi0, lane, fz3_0, fz7_0);
  expz_fin(p1, pi1, lane, fz3_1, fz7_1);

  // ---- MLP: lane j (=l5, j<15) computes hidden unit j ---------------------
  const int j = (l5 < 15) ? l5 : 0;
  float acc = W1[j * 4 + 0] * fz3_0 + W1[j * 4 + 1] * fz7_0 +
              W1[j * 4 + 2] * fz3_1 + W1[j * 4 + 3] * fz7_1 + b1[j];
  float e2 = __expf(2.0f * acc);
  float th = (e2 - 1.0f) / (e2 + 1.0f);
  float part = (l5 < 15) ? th * W2[j] : 0.0f;
  #pragma unroll
  for (int m = 1; m < 32; m <<= 1) part += __shfl_xor(part, m);

  if (l5 == 0 && elem < B) {
    float z = part + b2[0];
    out[elem] = 1.0f / (1.0f + __expf(-z));
  }
}

extern "C" void kernel_launch(void* const* d_in, const int* in_sizes, int n_in,
                              void* d_out, int out_size, void* d_ws, size_t ws_size,
                              hipStream_t stream) {
  (void)n_in; (void)out_size; (void)d_ws; (void)ws_size;
  const float* x     = (const float*)d_in[0];
  const float* rz_p  = (const float*)d_in[1];
  const float* ry_p  = (const float*)d_in[2];
  const float* ry2_p = (const float*)d_in[3];
  const float* crx_p = (const float*)d_in[4];
  const float* u3_p  = (const float*)d_in[5];
  const float* u3b_p = (const float*)d_in[6];
  const float* W1    = (const float*)d_in[7];
  const float* b1    = (const float*)d_in[8];
  const float* W2    = (const float*)d_in[9];
  const float* b2    = (const float*)d_in[10];
  float* out = (float*)d_out;

  const int B = in_sizes[0] / 32;          // 8192
  const int blocks = (B + 7) / 8;          // 2 elems/wave, 4 waves/block
  qcnn_kernel<<<dim3(blocks), dim3(256), 0, stream>>>(
      x, rz_p, ry_p, ry2_p, crx_p, u3_p, u3b_p, W1, b1, W2, b2, out, B);
}